// Round 7
// baseline (15834.749 us; speedup 1.0000x reference)
//
#include <hip/hip_runtime.h>
#include <cstdint>
#include <cstddef>

// Problem dims
#define TT 512   // timesteps
#define BB 32    // batch
#define II 512   // input dim
#define HH 1024  // hidden dim
#define OO 256   // output dim
#define GG 4096  // 4*H

typedef __attribute__((ext_vector_type(8))) short short8;
typedef __attribute__((ext_vector_type(4))) float f32x4;

__device__ __forceinline__ unsigned short f2bf(float f) {
  unsigned u = __float_as_uint(f);
  u = (u + 0x7FFFu + ((u >> 16) & 1u)) >> 16;  // RNE truncation (inputs finite)
  return (unsigned short)u;
}
__device__ __forceinline__ float bf2f(unsigned short s) {
  return __uint_as_float(((unsigned)s) << 16);
}
__device__ __forceinline__ short8 pack8(f32x4 lo, f32x4 hi) {
  short8 v;
  v[0] = (short)f2bf(lo[0]); v[1] = (short)f2bf(lo[1]);
  v[2] = (short)f2bf(lo[2]); v[3] = (short)f2bf(lo[3]);
  v[4] = (short)f2bf(hi[0]); v[5] = (short)f2bf(hi[1]);
  v[6] = (short)f2bf(hi[2]); v[7] = (short)f2bf(hi[3]);
  return v;
}

// ---------- fp32 -> bf16 bulk convert (8 elems/thread) ----------
__global__ __launch_bounds__(256) void k_convert(const float* __restrict__ in,
                                                 unsigned short* __restrict__ out,
                                                 int n8) {
  int i = blockIdx.x * 256 + threadIdx.x;
  if (i >= n8) return;
  const f32x4* p = (const f32x4*)in + (size_t)i * 2;
  f32x4 a = p[0], b = p[1];
  *((short8*)out + i) = pack8(a, b);
}

// ---------- xg[t][g][b] = dot(x[b][t][:], W_ih[g][:]) + b_ih[g] + b_hh[g] ----------
__global__ __launch_bounds__(256) void k_xg(const unsigned short* __restrict__ xb,
                                            const unsigned short* __restrict__ wb,
                                            const float* __restrict__ bih,
                                            const float* __restrict__ bhh,
                                            unsigned short* __restrict__ xg) {
  int t = blockIdx.y;
  int g0 = blockIdx.x * 64;
  int wave = threadIdx.x >> 6, lane = threadIdx.x & 63;
  int lr = lane & 15, ko = lane >> 4;
  int rowA = g0 + wave * 16 + lr;
  int rD = g0 + wave * 16 + ko * 4;
  f32x4 bias = *(const f32x4*)(bih + rD);
  bias += *(const f32x4*)(bhh + rD);
  f32x4 acc0 = bias, acc1 = bias;
  const short8* arow = (const short8*)(wb + (size_t)rowA * II);
#pragma unroll
  for (int ks = 0; ks < 16; ++ks) {
    int k = ks * 32 + ko * 8;
    short8 a = arow[k >> 3];
    short8 b0 = *(const short8*)(xb + ((size_t)lr * TT + t) * II + k);
    short8 b1 = *(const short8*)(xb + ((size_t)(lr + 16) * TT + t) * II + k);
    acc0 = __builtin_amdgcn_mfma_f32_16x16x32_bf16(a, b0, acc0, 0, 0, 0);
    acc1 = __builtin_amdgcn_mfma_f32_16x16x32_bf16(a, b1, acc1, 0, 0, 0);
  }
  size_t base = (size_t)t * GG * BB;
#pragma unroll
  for (int q = 0; q < 4; ++q) {
    xg[base + (size_t)(rD + q) * BB + lr] = f2bf(acc0[q]);
    xg[base + (size_t)(rD + q) * BB + 16 + lr] = f2bf(acc1[q]);
  }
}

// ---------- grid barrier (padded flags: stride 32 dwords = 128 B/flag) ----------
__device__ __forceinline__ void gridbar_pad(unsigned* flags, int p, unsigned gen, int tid) {
  asm volatile("s_waitcnt vmcnt(0)" ::: "memory");
  __syncthreads();
  if (tid == 0)
    __hip_atomic_store(flags + (p << 5), gen, __ATOMIC_RELAXED, __HIP_MEMORY_SCOPE_AGENT);
  if (tid < 64) {
    int it = 0;
    for (;;) {
      unsigned v = __hip_atomic_load(flags + (tid << 5), __ATOMIC_RELAXED, __HIP_MEMORY_SCOPE_AGENT);
      if (v >= gen) break;
      __builtin_amdgcn_s_sleep(1);
      if (++it > (1 << 24)) break;  // hang-safety
    }
    __builtin_amdgcn_fence(__ATOMIC_ACQUIRE, "agent");  // single L1+L2 inv
  }
  asm volatile("" ::: "memory");
  __syncthreads();
}

// ---------- persistent LSTM scan (round-6 structure + 2 micro-fixes) ----------
// Micro-fix 1: xg prefetch moved INTO the poll window (after flag store) so its
// HBM latency hides under the wait and its drain leaves the serial path.
// Micro-fix 2: flags padded to 128 B each (poll traffic spread across L3 slices,
// no write-starvation of the flag store).
__global__ __launch_bounds__(512, 2) void k_scan(const float* __restrict__ whh,
                                                 const unsigned short* __restrict__ xg,
                                                 const float* __restrict__ h0,
                                                 const float* __restrict__ c0,
                                                 unsigned short* __restrict__ hbuf,
                                                 unsigned short* __restrict__ hs,
                                                 float* __restrict__ tail,
                                                 unsigned* __restrict__ flags) {
  int p = blockIdx.x;
  int j0 = p * 16;
  int tid = threadIdx.x;
  int wave = tid >> 6, lane = tid & 63;
  int m = wave >> 1, n = wave & 1;
  int lr = lane & 15, ko = lane >> 4;

  __shared__ float gates[64][36];

  short8 aW[32];
  {
    const float* wr = whh + (size_t)(m * HH + j0 + lr) * HH + ko * 8;
#pragma unroll
    for (int ks = 0; ks < 32; ++ks) {
      f32x4 lo = *(const f32x4*)(wr + ks * 32);
      f32x4 hi = *(const f32x4*)(wr + ks * 32 + 4);
      aW[ks] = pack8(lo, hi);
    }
  }

  int jj = tid & 15, b = tid >> 4;
  float c = c0[b * HH + j0 + jj];
  {
    unsigned hv = f2bf(h0[b * HH + j0 + jj]);
    unsigned up = __shfl_down(hv, 1);
    if (!(jj & 1)) {
      size_t e = (size_t)b * HH + j0 + jj;
      __hip_atomic_store((unsigned*)hbuf + (e >> 1), hv | (up << 16),
                         __ATOMIC_RELAXED, __HIP_MEMORY_SCOPE_AGENT);
    }
  }
  gridbar_pad(flags, p, 1u, tid);

  const unsigned short* xp = xg + (size_t)(j0 + jj) * BB + b;
  unsigned short xi = xp[0];
  unsigned short xf = xp[(size_t)HH * BB];
  unsigned short xc = xp[(size_t)2 * HH * BB];
  unsigned short xo = xp[(size_t)3 * HH * BB];

  for (int t = 0; t < TT; ++t) {
    const unsigned short* hb =
        hbuf + (size_t)(t & 1) * BB * HH + (size_t)(n * 16 + lr) * HH + ko * 8;
    f32x4 acc0 = {0.f, 0.f, 0.f, 0.f}, acc1 = {0.f, 0.f, 0.f, 0.f};
#pragma unroll
    for (int ks = 0; ks < 32; ks += 2) {
      short8 bf0 = *(const short8*)(hb + ks * 32);
      short8 bf1 = *(const short8*)(hb + ks * 32 + 32);
      acc0 = __builtin_amdgcn_mfma_f32_16x16x32_bf16(aW[ks], bf0, acc0, 0, 0, 0);
      acc1 = __builtin_amdgcn_mfma_f32_16x16x32_bf16(aW[ks + 1], bf1, acc1, 0, 0, 0);
    }
    f32x4 acc = acc0 + acc1;
    {
      int r0 = m * 16 + ko * 4, cD = n * 16 + lr;
      gates[r0 + 0][cD] = acc[0];
      gates[r0 + 1][cD] = acc[1];
      gates[r0 + 2][cD] = acc[2];
      gates[r0 + 3][cD] = acc[3];
    }
    __syncthreads();

    // ---- update: gate order [i, f, g, o]
    float gi = gates[jj][b]      + bf2f(xi);
    float gf = gates[16 + jj][b] + bf2f(xf);
    float gc = gates[32 + jj][b] + bf2f(xc);
    float go = gates[48 + jj][b] + bf2f(xo);
    float ig = 1.f / (1.f + __expf(-gi));
    float fg = 1.f / (1.f + __expf(-gf));
    float ag = fabsf(gc), eg = __expf(-2.f * ag);
    float tg = (1.f - eg) / (1.f + eg); tg = gc < 0.f ? -tg : tg;
    float og = 1.f / (1.f + __expf(-go));
    c = fg * c + ig * tg;
    float ac = fabsf(c), ec = __expf(-2.f * ac);
    float tc = (1.f - ec) / (1.f + ec); tc = c < 0.f ? -tc : tc;
    float h = og * tc;
    unsigned short h16 = f2bf(h);
    {
      unsigned hv = h16;
      unsigned up = __shfl_down(hv, 1);
      if (!(jj & 1)) {
        size_t e = (size_t)((t + 1) & 1) * BB * HH + (size_t)b * HH + j0 + jj;
        __hip_atomic_store((unsigned*)hbuf + (e >> 1), hv | (up << 16),
                           __ATOMIC_RELAXED, __HIP_MEMORY_SCOPE_AGENT);
      }
    }
    hs[((size_t)b * TT + t) * HH + j0 + jj] = h16;
    if (t == TT - 1) {
      tail[b * HH + j0 + jj] = h;             // hT
      tail[BB * HH + b * HH + j0 + jj] = c;   // cT
    }

    unsigned short nxi = 0, nxf = 0, nxc = 0, nxo = 0;
    if (t < TT - 1) {
      // inline barrier with xg prefetch inside the poll window
      asm volatile("s_waitcnt vmcnt(0)" ::: "memory");
      __syncthreads();
      if (tid == 0)
        __hip_atomic_store(flags + (p << 5), (unsigned)(t + 2),
                           __ATOMIC_RELAXED, __HIP_MEMORY_SCOPE_AGENT);
      {
        const unsigned short* q = xp + (size_t)(t + 1) * GG * BB;
        nxi = q[0];
        nxf = q[(size_t)HH * BB];
        nxc = q[(size_t)2 * HH * BB];
        nxo = q[(size_t)3 * HH * BB];
      }
      if (tid < 64) {
        int it = 0;
        for (;;) {
          unsigned v = __hip_atomic_load(flags + (tid << 5), __ATOMIC_RELAXED, __HIP_MEMORY_SCOPE_AGENT);
          if (v >= (unsigned)(t + 2)) break;
          __builtin_amdgcn_s_sleep(1);
          if (++it > (1 << 24)) break;
        }
        __builtin_amdgcn_fence(__ATOMIC_ACQUIRE, "agent");
      }
      asm volatile("" ::: "memory");
      __syncthreads();
    }
    xi = nxi; xf = nxf; xc = nxc; xo = nxo;
  }
}

// ---------- ABLATION C: compute path only (no cross-block protocol) ----------
// Full GEMM + LDS + update + publish stores, syncthreads only. 1024 iters so the
// dispatch is long enough to surface in the top-5 table. Outputs -> dead scratch.
__global__ __launch_bounds__(512, 2) void k_ablC(const float* __restrict__ whh,
                                                 const unsigned short* __restrict__ xg,
                                                 unsigned short* __restrict__ hbuf,
                                                 unsigned short* __restrict__ hs) {
  int p = blockIdx.x;
  int j0 = p * 16;
  int tid = threadIdx.x;
  int wave = tid >> 6, lane = tid & 63;
  int m = wave >> 1, n = wave & 1;
  int lr = lane & 15, ko = lane >> 4;
  __shared__ float gates[64][36];
  short8 aW[32];
  {
    const float* wr = whh + (size_t)(m * HH + j0 + lr) * HH + ko * 8;
#pragma unroll
    for (int ks = 0; ks < 32; ++ks) {
      f32x4 lo = *(const f32x4*)(wr + ks * 32);
      f32x4 hi = *(const f32x4*)(wr + ks * 32 + 4);
      aW[ks] = pack8(lo, hi);
    }
  }
  int jj = tid & 15, b = tid >> 4;
  float c = 0.f;
  const unsigned short* xp = xg + (size_t)(j0 + jj) * BB + b;
  unsigned short xi = 0, xf = 0, xc = 0, xo = 0;
  for (int t = 0; t < 1024; ++t) {
    int tm = t & (TT - 1);
    const unsigned short* hb =
        hbuf + (size_t)(t & 1) * BB * HH + (size_t)(n * 16 + lr) * HH + ko * 8;
    f32x4 acc0 = {0.f, 0.f, 0.f, 0.f}, acc1 = {0.f, 0.f, 0.f, 0.f};
#pragma unroll
    for (int ks = 0; ks < 32; ks += 2) {
      short8 bf0 = *(const short8*)(hb + ks * 32);
      short8 bf1 = *(const short8*)(hb + ks * 32 + 32);
      acc0 = __builtin_amdgcn_mfma_f32_16x16x32_bf16(aW[ks], bf0, acc0, 0, 0, 0);
      acc1 = __builtin_amdgcn_mfma_f32_16x16x32_bf16(aW[ks + 1], bf1, acc1, 0, 0, 0);
    }
    f32x4 acc = acc0 + acc1;
    {
      int r0 = m * 16 + ko * 4, cD = n * 16 + lr;
      gates[r0 + 0][cD] = acc[0];
      gates[r0 + 1][cD] = acc[1];
      gates[r0 + 2][cD] = acc[2];
      gates[r0 + 3][cD] = acc[3];
    }
    unsigned short nxi = 0, nxf = 0, nxc = 0, nxo = 0;
    {
      const unsigned short* q = xp + (size_t)tm * GG * BB;
      nxi = q[0];
      nxf = q[(size_t)HH * BB];
      nxc = q[(size_t)2 * HH * BB];
      nxo = q[(size_t)3 * HH * BB];
    }
    __syncthreads();
    float gi = gates[jj][b]      + bf2f(xi);
    float gf = gates[16 + jj][b] + bf2f(xf);
    float gc = gates[32 + jj][b] + bf2f(xc);
    float go = gates[48 + jj][b] + bf2f(xo);
    float ig = 1.f / (1.f + __expf(-gi));
    float fg = 1.f / (1.f + __expf(-gf));
    float ag = fabsf(gc), eg = __expf(-2.f * ag);
    float tg = (1.f - eg) / (1.f + eg); tg = gc < 0.f ? -tg : tg;
    float og = 1.f / (1.f + __expf(-go));
    c = fg * c + ig * tg;
    float ac = fabsf(c), ec = __expf(-2.f * ac);
    float tc = (1.f - ec) / (1.f + ec); tc = c < 0.f ? -tc : tc;
    float h = og * tc;
    unsigned short h16 = f2bf(h);
    {
      unsigned hv = h16;
      unsigned up = __shfl_down(hv, 1);
      if (!(jj & 1)) {
        size_t e = (size_t)((t + 1) & 1) * BB * HH + (size_t)b * HH + j0 + jj;
        __hip_atomic_store((unsigned*)hbuf + (e >> 1), hv | (up << 16),
                           __ATOMIC_RELAXED, __HIP_MEMORY_SCOPE_AGENT);
      }
    }
    hs[((size_t)b * TT + tm) * HH + j0 + jj] = h16;
    xi = nxi; xf = nxf; xc = nxc; xo = nxo;
    __syncthreads();
  }
}

// ---------- ABLATION D: barrier + publish only (no GEMM/update) ----------
// Measures the pure sync protocol: h publish + drain + flag + poll + fence.
__global__ __launch_bounds__(512, 2) void k_ablD(unsigned short* __restrict__ hbuf,
                                                 unsigned* __restrict__ flags) {
  int p = blockIdx.x;
  int tid = threadIdx.x;
  int jj = tid & 15, b = tid >> 4, j0 = p * 16;
  for (int t = 0; t < 1024; ++t) {
    unsigned hv = (unsigned)(t + tid) & 0xFFFFu;
    unsigned up = __shfl_down(hv, 1);
    if (!(jj & 1)) {
      size_t e = (size_t)((t + 1) & 1) * BB * HH + (size_t)b * HH + j0 + jj;
      __hip_atomic_store((unsigned*)hbuf + (e >> 1), hv | (up << 16),
                         __ATOMIC_RELAXED, __HIP_MEMORY_SCOPE_AGENT);
    }
    asm volatile("s_waitcnt vmcnt(0)" ::: "memory");
    __syncthreads();
    if (tid == 0)
      __hip_atomic_store(flags + (p << 5), (unsigned)(t + 1),
                         __ATOMIC_RELAXED, __HIP_MEMORY_SCOPE_AGENT);
    if (tid < 64) {
      int it = 0;
      for (;;) {
        unsigned v = __hip_atomic_load(flags + (tid << 5), __ATOMIC_RELAXED, __HIP_MEMORY_SCOPE_AGENT);
        if (v >= (unsigned)(t + 1)) break;
        __builtin_amdgcn_s_sleep(1);
        if (++it > (1 << 24)) break;
      }
      __builtin_amdgcn_fence(__ATOMIC_ACQUIRE, "agent");
    }
    asm volatile("" ::: "memory");
    __syncthreads();
  }
}

// ---------- out[m][n] = dot(hs[m][:], fc_W[n][:]) + fc_b[n] ----------
__global__ __launch_bounds__(256) void k_fc(const unsigned short* __restrict__ hs,
                                            const unsigned short* __restrict__ fw,
                                            const float* __restrict__ fb,
                                            float* __restrict__ out) {
  int mb = blockIdx.x * 64, nb = blockIdx.y * 64;
  int wave = threadIdx.x >> 6, lane = threadIdx.x & 63;
  int lr = lane & 15, ko = lane >> 4;
  int rowA = mb + wave * 16 + lr;
  f32x4 acc[4] = {{0, 0, 0, 0}, {0, 0, 0, 0}, {0, 0, 0, 0}, {0, 0, 0, 0}};
#pragma unroll 8
  for (int ks = 0; ks < 32; ++ks) {
    int k = ks * 32 + ko * 8;
    short8 a = *(const short8*)(hs + (size_t)rowA * HH + k);
#pragma unroll
    for (int nt = 0; nt < 4; ++nt) {
      short8 bb = *(const short8*)(fw + (size_t)(nb + nt * 16 + lr) * HH + k);
      acc[nt] = __builtin_amdgcn_mfma_f32_16x16x32_bf16(a, bb, acc[nt], 0, 0, 0);
    }
  }
  int rD = mb + wave * 16 + ko * 4;
#pragma unroll
  for (int nt = 0; nt < 4; ++nt) {
    int col = nb + nt * 16 + lr;
    float bias = fb[col];
#pragma unroll
    for (int q = 0; q < 4; ++q)
      out[(size_t)(rD + q) * OO + col] = acc[nt][q] + bias;
  }
}

extern "C" void kernel_launch(void* const* d_in, const int* in_sizes, int n_in,
                              void* d_out, int out_size, void* d_ws, size_t ws_size,
                              hipStream_t stream) {
  (void)in_sizes; (void)n_in; (void)out_size; (void)ws_size;
  const float* x   = (const float*)d_in[0];
  const float* h0  = (const float*)d_in[1];
  const float* c0  = (const float*)d_in[2];
  const float* wih = (const float*)d_in[3];
  const float* whh = (const float*)d_in[4];
  const float* bih = (const float*)d_in[5];
  const float* bhh = (const float*)d_in[6];
  const float* fcw = (const float*)d_in[7];
  const float* fcb = (const float*)d_in[8];
  float* out = (float*)d_out;

  // workspace carve (~181 MB)
  char* w = (char*)d_ws;
  unsigned short* xg   = (unsigned short*)w; w += (size_t)TT * GG * BB * 2;  // 128 MiB
  unsigned short* hsb  = (unsigned short*)w; w += (size_t)BB * TT * HH * 2;  //  32 MiB
  unsigned short* xb   = (unsigned short*)w; w += (size_t)BB * TT * II * 2;  //  16 MiB
  unsigned short* wbb  = (unsigned short*)w; w += (size_t)GG * II * 2;       //   4 MiB
  unsigned short* fwb  = (unsigned short*)w; w += (size_t)OO * HH * 2;       // 512 KiB
  unsigned short* hbuf = (unsigned short*)w; w += (size_t)2 * BB * HH * 2;   // 128 KiB
  unsigned* flags      = (unsigned*)w;       w += 8192;                      // 64 x 128 B
  unsigned* flagsD     = (unsigned*)w;       w += 8192;

  // ablation scratch aliases into xg (dead after the real k_scan)
  unsigned short* hbuf_C = xg;
  unsigned short* hs_C   = (unsigned short*)((char*)xg + ((size_t)64 << 20));
  unsigned short* hbuf_D = (unsigned short*)((char*)xg + ((size_t)32 << 20));

  hipMemsetAsync(flags, 0, 16384, stream);
  k_convert<<<(BB * TT * II / 8) / 256, 256, 0, stream>>>(x, xb, BB * TT * II / 8);
  k_convert<<<(GG * II / 8) / 256, 256, 0, stream>>>(wih, wbb, GG * II / 8);
  k_convert<<<(OO * HH / 8) / 256, 256, 0, stream>>>(fcw, fwb, OO * HH / 8);
  k_xg<<<dim3(64, TT), 256, 0, stream>>>(xb, wbb, bih, bhh, xg);
  k_scan<<<64, 512, 0, stream>>>(whh, xg, h0, c0, hbuf, hsb,
                                 out + (size_t)BB * TT * OO, flags);
  k_fc<<<dim3(BB * TT / 64, OO / 64), 256, 0, stream>>>(hsb, fwb, fcb, out);
  // instrumentation dispatches (outputs to dead scratch; 1024 iters for top-5 visibility)
  k_ablC<<<64, 512, 0, stream>>>(whh, xg, hbuf_C, hs_C);
  k_ablD<<<64, 512, 0, stream>>>(hbuf_D, flagsD);
}

// Round 8
// 3241.642 us; speedup vs baseline: 4.8848x; 4.8848x over previous
//
#include <hip/hip_runtime.h>
#include <cstdint>
#include <cstddef>

// Problem dims
#define TT 512   // timesteps
#define BB 32    // batch
#define II 512   // input dim
#define HH 1024  // hidden dim
#define OO 256   // output dim
#define GG 4096  // 4*H

typedef __attribute__((ext_vector_type(8))) short short8;
typedef __attribute__((ext_vector_type(4))) float f32x4;

__device__ __forceinline__ unsigned short f2bf(float f) {
  unsigned u = __float_as_uint(f);
  u = (u + 0x7FFFu + ((u >> 16) & 1u)) >> 16;  // RNE truncation (inputs finite)
  return (unsigned short)u;
}
__device__ __forceinline__ float bf2f(unsigned short s) {
  return __uint_as_float(((unsigned)s) << 16);
}
__device__ __forceinline__ short8 pack8(f32x4 lo, f32x4 hi) {
  short8 v;
  v[0] = (short)f2bf(lo[0]); v[1] = (short)f2bf(lo[1]);
  v[2] = (short)f2bf(lo[2]); v[3] = (short)f2bf(lo[3]);
  v[4] = (short)f2bf(hi[0]); v[5] = (short)f2bf(hi[1]);
  v[6] = (short)f2bf(hi[2]); v[7] = (short)f2bf(hi[3]);
  return v;
}

// ---------- fp32 -> bf16 bulk convert (8 elems/thread) ----------
__global__ __launch_bounds__(256) void k_convert(const float* __restrict__ in,
                                                 unsigned short* __restrict__ out,
                                                 int n8) {
  int i = blockIdx.x * 256 + threadIdx.x;
  if (i >= n8) return;
  const f32x4* p = (const f32x4*)in + (size_t)i * 2;
  f32x4 a = p[0], b = p[1];
  *((short8*)out + i) = pack8(a, b);
}

// ---------- xg[t][g][b] = dot(x[b][t][:], W_ih[g][:]) + b_ih[g] + b_hh[g] ----------
__global__ __launch_bounds__(256) void k_xg(const unsigned short* __restrict__ xb,
                                            const unsigned short* __restrict__ wb,
                                            const float* __restrict__ bih,
                                            const float* __restrict__ bhh,
                                            unsigned short* __restrict__ xg) {
  int t = blockIdx.y;
  int g0 = blockIdx.x * 64;
  int wave = threadIdx.x >> 6, lane = threadIdx.x & 63;
  int lr = lane & 15, ko = lane >> 4;
  int rowA = g0 + wave * 16 + lr;
  int rD = g0 + wave * 16 + ko * 4;
  f32x4 bias = *(const f32x4*)(bih + rD);
  bias += *(const f32x4*)(bhh + rD);
  f32x4 acc0 = bias, acc1 = bias;
  const short8* arow = (const short8*)(wb + (size_t)rowA * II);
#pragma unroll
  for (int ks = 0; ks < 16; ++ks) {
    int k = ks * 32 + ko * 8;
    short8 a = arow[k >> 3];
    short8 b0 = *(const short8*)(xb + ((size_t)lr * TT + t) * II + k);
    short8 b1 = *(const short8*)(xb + ((size_t)(lr + 16) * TT + t) * II + k);
    acc0 = __builtin_amdgcn_mfma_f32_16x16x32_bf16(a, b0, acc0, 0, 0, 0);
    acc1 = __builtin_amdgcn_mfma_f32_16x16x32_bf16(a, b1, acc1, 0, 0, 0);
  }
  size_t base = (size_t)t * GG * BB;
#pragma unroll
  for (int q = 0; q < 4; ++q) {
    xg[base + (size_t)(rD + q) * BB + lr] = f2bf(acc0[q]);
    xg[base + (size_t)(rD + q) * BB + 16 + lr] = f2bf(acc1[q]);
  }
}

// ---------- grid barrier (round-6 winner: padded flags, relaxed poll, one inv) ----------
__device__ __forceinline__ void gridbar_pad(unsigned* flags, int p, unsigned gen, int tid) {
  asm volatile("s_waitcnt vmcnt(0)" ::: "memory");
  __syncthreads();
  if (tid == 0)
    __hip_atomic_store(flags + (p << 5), gen, __ATOMIC_RELAXED, __HIP_MEMORY_SCOPE_AGENT);
  if (tid < 64) {
    int it = 0;
    for (;;) {
      unsigned v = __hip_atomic_load(flags + (tid << 5), __ATOMIC_RELAXED, __HIP_MEMORY_SCOPE_AGENT);
      if (v >= gen) break;
      __builtin_amdgcn_s_sleep(1);
      if (++it > (1 << 24)) break;  // hang-safety
    }
    __builtin_amdgcn_fence(__ATOMIC_ACQUIRE, "agent");  // single L1+L2 inv
  }
  asm volatile("" ::: "memory");
  __syncthreads();
}

// ---------- persistent LSTM scan — K-split wave remap (kills 4x h re-read) ----------
// 64 blocks x 512 thr (8 waves). Block p owns h-cols j0=p*16..+15 (64 W_hh rows).
// Wave = (kq = K-quarter 0..3, n = batch-half 0..1). Each wave reads a DISJOINT
// 8 KB h-slice (8 short8 loads/step; block traffic 64 KB, was 256 KB) and
// computes partial gate sums for ALL 4 gates over its K-quarter: 32 MFMA/wave.
// Partials reduced via LDS gp[4][64][36] in the update phase (16 reads + 12 adds).
// aW = 4 gates x 8 ks = 32 short8 (128 VGPR), persistent.
__global__ __launch_bounds__(512, 2) void k_scan(const float* __restrict__ whh,
                                                 const unsigned short* __restrict__ xg,
                                                 const float* __restrict__ h0,
                                                 const float* __restrict__ c0,
                                                 unsigned short* __restrict__ hbuf,
                                                 unsigned short* __restrict__ hs,
                                                 float* __restrict__ tail,
                                                 unsigned* __restrict__ flags) {
  int p = blockIdx.x;
  int j0 = p * 16;
  int tid = threadIdx.x;
  int wave = tid >> 6, lane = tid & 63;
  int kq = wave >> 1, n = wave & 1;   // kq: K-quarter, n: batch half
  int lr = lane & 15, ko = lane >> 4;

  __shared__ float gp[4][64][36];     // [kq][gate*16+jj][b], padded stride 36

  // persistent A-frags: aW[m*8+ks] = W_hh[m*HH + j0 + lr][kq*256 + ks*32 + ko*8 ..+8]
  short8 aW[32];
  {
    const float* wr = whh + (size_t)(j0 + lr) * HH + kq * 256 + ko * 8;
#pragma unroll
    for (int m = 0; m < 4; ++m)
#pragma unroll
      for (int ks = 0; ks < 8; ++ks) {
        const float* s = wr + (size_t)m * HH * HH + ks * 32;
        aW[m * 8 + ks] = pack8(*(const f32x4*)s, *(const f32x4*)(s + 4));
      }
  }

  // update-phase identity: thread owns (b, jj)
  int jj = tid & 15, b = tid >> 4;
  float c = c0[b * HH + j0 + jj];
  {
    unsigned hv = f2bf(h0[b * HH + j0 + jj]);
    unsigned up = __shfl_down(hv, 1);
    if (!(jj & 1)) {
      size_t e = (size_t)b * HH + j0 + jj;
      __hip_atomic_store((unsigned*)hbuf + (e >> 1), hv | (up << 16),
                         __ATOMIC_RELAXED, __HIP_MEMORY_SCOPE_AGENT);
    }
  }
  gridbar_pad(flags, p, 1u, tid);

  // xg register prefetch (t = 0)
  const unsigned short* xp = xg + (size_t)(j0 + jj) * BB + b;
  unsigned short xi = xp[0];
  unsigned short xf = xp[(size_t)HH * BB];
  unsigned short xc = xp[(size_t)2 * HH * BB];
  unsigned short xo = xp[(size_t)3 * HH * BB];

  for (int t = 0; t < TT; ++t) {
    // ---- partial GEMM: this wave's disjoint h-slice, all 4 gates
    const unsigned short* hb = hbuf + (size_t)(t & 1) * BB * HH +
                               (size_t)(n * 16 + lr) * HH + kq * 256 + ko * 8;
    short8 bf[8];
#pragma unroll
    for (int ks = 0; ks < 8; ++ks) bf[ks] = *(const short8*)(hb + ks * 32);
    f32x4 a0 = {0.f, 0.f, 0.f, 0.f}, a1 = a0, a2 = a0, a3 = a0;
#pragma unroll
    for (int ks = 0; ks < 8; ++ks) {
      a0 = __builtin_amdgcn_mfma_f32_16x16x32_bf16(aW[ks], bf[ks], a0, 0, 0, 0);
      a1 = __builtin_amdgcn_mfma_f32_16x16x32_bf16(aW[8 + ks], bf[ks], a1, 0, 0, 0);
      a2 = __builtin_amdgcn_mfma_f32_16x16x32_bf16(aW[16 + ks], bf[ks], a2, 0, 0, 0);
      a3 = __builtin_amdgcn_mfma_f32_16x16x32_bf16(aW[24 + ks], bf[ks], a3, 0, 0, 0);
    }
    {
      int cD = n * 16 + lr, r0 = ko * 4;
#pragma unroll
      for (int q = 0; q < 4; ++q) {
        gp[kq][r0 + q][cD]      = a0[q];
        gp[kq][16 + r0 + q][cD] = a1[q];
        gp[kq][32 + r0 + q][cD] = a2[q];
        gp[kq][48 + r0 + q][cD] = a3[q];
      }
    }
    __syncthreads();

    // ---- update: sum 4 K-quarter partials per gate; order [i, f, g, o]
    float gi = gp[0][jj][b] + gp[1][jj][b] + gp[2][jj][b] + gp[3][jj][b] + bf2f(xi);
    float gf = gp[0][16 + jj][b] + gp[1][16 + jj][b] + gp[2][16 + jj][b] + gp[3][16 + jj][b] + bf2f(xf);
    float gc = gp[0][32 + jj][b] + gp[1][32 + jj][b] + gp[2][32 + jj][b] + gp[3][32 + jj][b] + bf2f(xc);
    float go = gp[0][48 + jj][b] + gp[1][48 + jj][b] + gp[2][48 + jj][b] + gp[3][48 + jj][b] + bf2f(xo);
    float ig = 1.f / (1.f + __expf(-gi));
    float fg = 1.f / (1.f + __expf(-gf));
    float ag = fabsf(gc), eg = __expf(-2.f * ag);
    float tg = (1.f - eg) / (1.f + eg); tg = gc < 0.f ? -tg : tg;
    float og = 1.f / (1.f + __expf(-go));
    c = fg * c + ig * tg;
    float ac = fabsf(c), ec = __expf(-2.f * ac);
    float tc = (1.f - ec) / (1.f + ec); tc = c < 0.f ? -tc : tc;
    float h = og * tc;
    unsigned short h16 = f2bf(h);
    {
      // h-publish FIRST so sc1 acks start draining earliest
      unsigned hv = h16;
      unsigned up = __shfl_down(hv, 1);
      if (!(jj & 1)) {
        size_t e = (size_t)((t + 1) & 1) * BB * HH + (size_t)b * HH + j0 + jj;
        __hip_atomic_store((unsigned*)hbuf + (e >> 1), hv | (up << 16),
                           __ATOMIC_RELAXED, __HIP_MEMORY_SCOPE_AGENT);
      }
    }
    hs[((size_t)b * TT + t) * HH + j0 + jj] = h16;
    if (t == TT - 1) {
      tail[b * HH + j0 + jj] = h;             // hT
      tail[BB * HH + b * HH + j0 + jj] = c;   // cT
    }

    unsigned short nxi = 0, nxf = 0, nxc = 0, nxo = 0;
    if (t < TT - 1) {
      // inline barrier; xg prefetch for t+1 hidden in the poll window
      asm volatile("s_waitcnt vmcnt(0)" ::: "memory");
      __syncthreads();
      if (tid == 0)
        __hip_atomic_store(flags + (p << 5), (unsigned)(t + 2),
                           __ATOMIC_RELAXED, __HIP_MEMORY_SCOPE_AGENT);
      {
        const unsigned short* q = xp + (size_t)(t + 1) * GG * BB;
        nxi = q[0];
        nxf = q[(size_t)HH * BB];
        nxc = q[(size_t)2 * HH * BB];
        nxo = q[(size_t)3 * HH * BB];
      }
      if (tid < 64) {
        int it = 0;
        for (;;) {
          unsigned v = __hip_atomic_load(flags + (tid << 5), __ATOMIC_RELAXED, __HIP_MEMORY_SCOPE_AGENT);
          if (v >= (unsigned)(t + 2)) break;
          __builtin_amdgcn_s_sleep(1);
          if (++it > (1 << 24)) break;
        }
        __builtin_amdgcn_fence(__ATOMIC_ACQUIRE, "agent");
      }
      asm volatile("" ::: "memory");
      __syncthreads();
    }
    xi = nxi; xf = nxf; xc = nxc; xo = nxo;
  }
}

// ---------- out[m][n] = dot(hs[m][:], fc_W[n][:]) + fc_b[n] ----------
__global__ __launch_bounds__(256) void k_fc(const unsigned short* __restrict__ hs,
                                            const unsigned short* __restrict__ fw,
                                            const float* __restrict__ fb,
                                            float* __restrict__ out) {
  int mb = blockIdx.x * 64, nb = blockIdx.y * 64;
  int wave = threadIdx.x >> 6, lane = threadIdx.x & 63;
  int lr = lane & 15, ko = lane >> 4;
  int rowA = mb + wave * 16 + lr;
  f32x4 acc[4] = {{0, 0, 0, 0}, {0, 0, 0, 0}, {0, 0, 0, 0}, {0, 0, 0, 0}};
#pragma unroll 8
  for (int ks = 0; ks < 32; ++ks) {
    int k = ks * 32 + ko * 8;
    short8 a = *(const short8*)(hs + (size_t)rowA * HH + k);
#pragma unroll
    for (int nt = 0; nt < 4; ++nt) {
      short8 bb = *(const short8*)(fw + (size_t)(nb + nt * 16 + lr) * HH + k);
      acc[nt] = __builtin_amdgcn_mfma_f32_16x16x32_bf16(a, bb, acc[nt], 0, 0, 0);
    }
  }
  int rD = mb + wave * 16 + ko * 4;
#pragma unroll
  for (int nt = 0; nt < 4; ++nt) {
    int col = nb + nt * 16 + lr;
    float bias = fb[col];
#pragma unroll
    for (int q = 0; q < 4; ++q)
      out[(size_t)(rD + q) * OO + col] = acc[nt][q] + bias;
  }
}

extern "C" void kernel_launch(void* const* d_in, const int* in_sizes, int n_in,
                              void* d_out, int out_size, void* d_ws, size_t ws_size,
                              hipStream_t stream) {
  (void)in_sizes; (void)n_in; (void)out_size; (void)ws_size;
  const float* x   = (const float*)d_in[0];
  const float* h0  = (const float*)d_in[1];
  const float* c0  = (const float*)d_in[2];
  const float* wih = (const float*)d_in[3];
  const float* whh = (const float*)d_in[4];
  const float* bih = (const float*)d_in[5];
  const float* bhh = (const float*)d_in[6];
  const float* fcw = (const float*)d_in[7];
  const float* fcb = (const float*)d_in[8];
  float* out = (float*)d_out;

  // workspace carve (~181 MB)
  char* w = (char*)d_ws;
  unsigned short* xg   = (unsigned short*)w; w += (size_t)TT * GG * BB * 2;  // 128 MiB
  unsigned short* hsb  = (unsigned short*)w; w += (size_t)BB * TT * HH * 2;  //  32 MiB
  unsigned short* xb   = (unsigned short*)w; w += (size_t)BB * TT * II * 2;  //  16 MiB
  unsigned short* wbb  = (unsigned short*)w; w += (size_t)GG * II * 2;       //   4 MiB
  unsigned short* fwb  = (unsigned short*)w; w += (size_t)OO * HH * 2;       // 512 KiB
  unsigned short* hbuf = (unsigned short*)w; w += (size_t)2 * BB * HH * 2;   // 128 KiB
  unsigned* flags      = (unsigned*)w;       w += 8192;                      // 64 x 128 B

  hipMemsetAsync(flags, 0, 8192, stream);
  k_convert<<<(BB * TT * II / 8) / 256, 256, 0, stream>>>(x, xb, BB * TT * II / 8);
  k_convert<<<(GG * II / 8) / 256, 256, 0, stream>>>(wih, wbb, GG * II / 8);
  k_convert<<<(OO * HH / 8) / 256, 256, 0, stream>>>(fcw, fwb, OO * HH / 8);
  k_xg<<<dim3(64, TT), 256, 0, stream>>>(xb, wbb, bih, bhh, xg);
  k_scan<<<64, 512, 0, stream>>>(whh, xg, h0, c0, hbuf, hsb,
                                 out + (size_t)BB * TT * OO, flags);
  k_fc<<<dim3(BB * TT / 64, OO / 64), 256, 0, stream>>>(hsb, fwb, fcb, out);
}

// Round 10
// 2592.343 us; speedup vs baseline: 6.1083x; 1.2505x over previous
//
#include <hip/hip_runtime.h>
#include <cstdint>
#include <cstddef>

// Problem dims
#define TT 512   // timesteps
#define BB 32    // batch
#define II 512   // input dim
#define HH 1024  // hidden dim
#define OO 256   // output dim
#define GG 4096  // 4*H

#define NSCAN 64   // scan blocks
#define NWORK 192  // xg worker blocks

typedef __attribute__((ext_vector_type(8))) short short8;
typedef __attribute__((ext_vector_type(4))) float f32x4;

__device__ __forceinline__ unsigned short f2bf(float f) {
  unsigned u = __float_as_uint(f);
  u = (u + 0x7FFFu + ((u >> 16) & 1u)) >> 16;  // RNE truncation (inputs finite)
  return (unsigned short)u;
}
__device__ __forceinline__ float bf2f(unsigned short s) {
  return __uint_as_float(((unsigned)s) << 16);
}
__device__ __forceinline__ short8 pack8(f32x4 lo, f32x4 hi) {
  short8 v;
  v[0] = (short)f2bf(lo[0]); v[1] = (short)f2bf(lo[1]);
  v[2] = (short)f2bf(lo[2]); v[3] = (short)f2bf(lo[3]);
  v[4] = (short)f2bf(hi[0]); v[5] = (short)f2bf(hi[1]);
  v[6] = (short)f2bf(hi[2]); v[7] = (short)f2bf(hi[3]);
  return v;
}

// ---------- fp32 -> bf16 bulk convert (8 elems/thread) ----------
__global__ __launch_bounds__(256) void k_convert(const float* __restrict__ in,
                                                 unsigned short* __restrict__ out,
                                                 int n8) {
  int i = blockIdx.x * 256 + threadIdx.x;
  if (i >= n8) return;
  const f32x4* p = (const f32x4*)in + (size_t)i * 2;
  f32x4 a = p[0], b = p[1];
  *((short8*)out + i) = pack8(a, b);
}

// =====================================================================
// Fused persistent kernel: blocks 0..63 = LSTM scan, 64..255 = xg workers.
//
// Workers compute xg[t][g][b] = x[b][t]·W_ih[g] + b_ih[g] + b_hh[g] and
// publish via sc1 (agent-scope relaxed atomic) dword stores -> L3, then
// bump done[t] (device atomicAdd) after a vmcnt drain. Work items are
// t-major so early timesteps complete first (workers run ~5x faster than
// the scan consumes).
//
// Scan blocks: round-8 K-split structure (wave = K-quarter x batch-half,
// disjoint h-slices, partial-gate MFMA, LDS reduce). The xg prefetch for
// t+1 (hidden in the barrier poll window) is gated on done[t+1]==32.
// Freshness of plain xg reads: scan XCDs never touch those lines between
// the per-step acquire-inv and the prefetch, so they L2-miss to L3 where
// the workers' sc1 stores landed.
// =====================================================================
__global__ __launch_bounds__(512, 2) void k_main(
    const float* __restrict__ whh,
    const unsigned short* __restrict__ xb,   // x bf16 [b][t][i]
    const unsigned short* __restrict__ wbb,  // W_ih bf16 [g][i]
    const float* __restrict__ bih,
    const float* __restrict__ bhh,
    unsigned short* __restrict__ xg,         // [t][g][b] bf16
    const float* __restrict__ h0,
    const float* __restrict__ c0,
    unsigned short* __restrict__ hbuf,
    unsigned short* __restrict__ hs,
    float* __restrict__ tail,
    unsigned* __restrict__ flags,            // 64 x 32-dword padded
    unsigned* __restrict__ done) {           // 512 x 32-dword padded counters
  __shared__ float gp[4][64][36];  // scan only: [kq][gate*16+jj][b]

  int tid = threadIdx.x;
  int wave = tid >> 6, lane = tid & 63;
  int lr = lane & 15, ko = lane >> 4;

  if (blockIdx.x >= NSCAN) {
    // ---------------- xg worker ----------------
    int wid = blockIdx.x - NSCAN;
    int wv = wave & 3, half = wave >> 2;  // wv: 16-row slice, half: gtile of pair
    for (int bi = wid; bi < TT * 32; bi += NWORK) {
      int t = bi >> 5, pr = bi & 31;
      int g0 = pr * 128 + half * 64;
      int rowA = g0 + wv * 16 + lr;
      int rD = g0 + wv * 16 + ko * 4;
      f32x4 bias = *(const f32x4*)(bih + rD);
      bias += *(const f32x4*)(bhh + rD);
      f32x4 acc0 = bias, acc1 = bias;
      const short8* arow = (const short8*)(wbb + (size_t)rowA * II);
#pragma unroll
      for (int ks = 0; ks < 16; ++ks) {
        int k = ks * 32 + ko * 8;
        short8 a = arow[k >> 3];
        short8 b0 = *(const short8*)(xb + ((size_t)lr * TT + t) * II + k);
        short8 b1 = *(const short8*)(xb + ((size_t)(lr + 16) * TT + t) * II + k);
        acc0 = __builtin_amdgcn_mfma_f32_16x16x32_bf16(a, b0, acc0, 0, 0, 0);
        acc1 = __builtin_amdgcn_mfma_f32_16x16x32_bf16(a, b1, acc1, 0, 0, 0);
      }
      // publish via sc1 dword stores (pack adjacent-b pairs with shfl)
      size_t base = (size_t)t * GG * BB;
#pragma unroll
      for (int q = 0; q < 4; ++q) {
        unsigned v0 = f2bf(acc0[q]);
        unsigned s0 = __shfl_down(v0, 1);
        unsigned v1 = f2bf(acc1[q]);
        unsigned s1 = __shfl_down(v1, 1);
        if (!(lr & 1)) {
          size_t e0 = base + (size_t)(rD + q) * BB + lr;
          __hip_atomic_store((unsigned*)xg + (e0 >> 1), v0 | (s0 << 16),
                             __ATOMIC_RELAXED, __HIP_MEMORY_SCOPE_AGENT);
          size_t e1 = base + (size_t)(rD + q) * BB + 16 + lr;
          __hip_atomic_store((unsigned*)xg + (e1 >> 1), v1 | (s1 << 16),
                             __ATOMIC_RELAXED, __HIP_MEMORY_SCOPE_AGENT);
        }
      }
      asm volatile("s_waitcnt vmcnt(0)" ::: "memory");  // stores at L3
      __syncthreads();
      if (tid == 0)
        __hip_atomic_fetch_add(done + ((size_t)t << 5), 1u,
                               __ATOMIC_RELAXED, __HIP_MEMORY_SCOPE_AGENT);
    }
    return;
  }

  // ---------------- LSTM scan ----------------
  int p = blockIdx.x;
  int j0 = p * 16;
  int kq = wave >> 1, n = wave & 1;  // kq: K-quarter, n: batch half

  // persistent A-frags: aW[m*8+ks] = W_hh[m*HH + j0 + lr][kq*256 + ks*32 + ko*8 ..+8]
  short8 aW[32];
  {
    const float* wr = whh + (size_t)(j0 + lr) * HH + kq * 256 + ko * 8;
#pragma unroll
    for (int m = 0; m < 4; ++m)
#pragma unroll
      for (int ks = 0; ks < 8; ++ks) {
        const float* s = wr + (size_t)m * HH * HH + ks * 32;
        aW[m * 8 + ks] = pack8(*(const f32x4*)s, *(const f32x4*)(s + 4));
      }
  }

  // update-phase identity: thread owns (b, jj)
  int jj = tid & 15, b = tid >> 4;
  float c = c0[b * HH + j0 + jj];
  {
    unsigned hv = f2bf(h0[b * HH + j0 + jj]);
    unsigned up = __shfl_down(hv, 1);
    if (!(jj & 1)) {
      size_t e = (size_t)b * HH + j0 + jj;
      __hip_atomic_store((unsigned*)hbuf + (e >> 1), hv | (up << 16),
                         __ATOMIC_RELAXED, __HIP_MEMORY_SCOPE_AGENT);
    }
  }
  // wait for xg[0] then prefetch it (registers survive later invs)
  if (tid == 0) {
    int it = 0;
    while (__hip_atomic_load(done, __ATOMIC_RELAXED, __HIP_MEMORY_SCOPE_AGENT) < 32u) {
      __builtin_amdgcn_s_sleep(1);
      if (++it > (1 << 24)) break;
    }
  }
  __syncthreads();
  const unsigned short* xp = xg + (size_t)(j0 + jj) * BB + b;
  unsigned short xi = xp[0];
  unsigned short xf = xp[(size_t)HH * BB];
  unsigned short xc = xp[(size_t)2 * HH * BB];
  unsigned short xo = xp[(size_t)3 * HH * BB];
  // init barrier (round-6 winner: padded flags, relaxed poll, one inv)
  {
    asm volatile("s_waitcnt vmcnt(0)" ::: "memory");
    __syncthreads();
    if (tid == 0)
      __hip_atomic_store(flags + (p << 5), 1u, __ATOMIC_RELAXED, __HIP_MEMORY_SCOPE_AGENT);
    if (tid < 64) {
      int it = 0;
      for (;;) {
        unsigned v = __hip_atomic_load(flags + (tid << 5), __ATOMIC_RELAXED, __HIP_MEMORY_SCOPE_AGENT);
        if (v >= 1u) break;
        __builtin_amdgcn_s_sleep(1);
        if (++it > (1 << 24)) break;
      }
      __builtin_amdgcn_fence(__ATOMIC_ACQUIRE, "agent");
    }
    asm volatile("" ::: "memory");
    __syncthreads();
  }

  for (int t = 0; t < TT; ++t) {
    // ---- partial GEMM: this wave's disjoint h-slice, all 4 gates
    const unsigned short* hb = hbuf + (size_t)(t & 1) * BB * HH +
                               (size_t)(n * 16 + lr) * HH + kq * 256 + ko * 8;
    short8 bf[8];
#pragma unroll
    for (int ks = 0; ks < 8; ++ks) bf[ks] = *(const short8*)(hb + ks * 32);
    f32x4 a0 = {0.f, 0.f, 0.f, 0.f}, a1 = a0, a2 = a0, a3 = a0;
#pragma unroll
    for (int ks = 0; ks < 8; ++ks) {
      a0 = __builtin_amdgcn_mfma_f32_16x16x32_bf16(aW[ks], bf[ks], a0, 0, 0, 0);
      a1 = __builtin_amdgcn_mfma_f32_16x16x32_bf16(aW[8 + ks], bf[ks], a1, 0, 0, 0);
      a2 = __builtin_amdgcn_mfma_f32_16x16x32_bf16(aW[16 + ks], bf[ks], a2, 0, 0, 0);
      a3 = __builtin_amdgcn_mfma_f32_16x16x32_bf16(aW[24 + ks], bf[ks], a3, 0, 0, 0);
    }
    {
      int cD = n * 16 + lr, r0 = ko * 4;
#pragma unroll
      for (int q = 0; q < 4; ++q) {
        gp[kq][r0 + q][cD]      = a0[q];
        gp[kq][16 + r0 + q][cD] = a1[q];
        gp[kq][32 + r0 + q][cD] = a2[q];
        gp[kq][48 + r0 + q][cD] = a3[q];
      }
    }
    __syncthreads();

    // ---- update: sum 4 K-quarter partials per gate; order [i, f, g, o]
    float gi = gp[0][jj][b] + gp[1][jj][b] + gp[2][jj][b] + gp[3][jj][b] + bf2f(xi);
    float gf = gp[0][16 + jj][b] + gp[1][16 + jj][b] + gp[2][16 + jj][b] + gp[3][16 + jj][b] + bf2f(xf);
    float gc = gp[0][32 + jj][b] + gp[1][32 + jj][b] + gp[2][32 + jj][b] + gp[3][32 + jj][b] + bf2f(xc);
    float go = gp[0][48 + jj][b] + gp[1][48 + jj][b] + gp[2][48 + jj][b] + gp[3][48 + jj][b] + bf2f(xo);
    float ig = 1.f / (1.f + __expf(-gi));
    float fg = 1.f / (1.f + __expf(-gf));
    float ag = fabsf(gc), eg = __expf(-2.f * ag);
    float tg = (1.f - eg) / (1.f + eg); tg = gc < 0.f ? -tg : tg;
    float og = 1.f / (1.f + __expf(-go));
    c = fg * c + ig * tg;
    float ac = fabsf(c), ec = __expf(-2.f * ac);
    float tc = (1.f - ec) / (1.f + ec); tc = c < 0.f ? -tc : tc;
    float h = og * tc;
    unsigned short h16 = f2bf(h);
    {
      unsigned hv = h16;
      unsigned up = __shfl_down(hv, 1);
      if (!(jj & 1)) {
        size_t e = (size_t)((t + 1) & 1) * BB * HH + (size_t)b * HH + j0 + jj;
        __hip_atomic_store((unsigned*)hbuf + (e >> 1), hv | (up << 16),
                           __ATOMIC_RELAXED, __HIP_MEMORY_SCOPE_AGENT);
      }
    }
    hs[((size_t)b * TT + t) * HH + j0 + jj] = h16;
    if (t == TT - 1) {
      tail[b * HH + j0 + jj] = h;             // hT
      tail[BB * HH + b * HH + j0 + jj] = c;   // cT
    }

    unsigned short nxi = 0, nxf = 0, nxc = 0, nxo = 0;
    if (t < TT - 1) {
      // inline barrier; xg readiness + prefetch hidden in the poll window
      asm volatile("s_waitcnt vmcnt(0)" ::: "memory");
      __syncthreads();
      if (tid == 0) {
        __hip_atomic_store(flags + (p << 5), (unsigned)(t + 2),
                           __ATOMIC_RELAXED, __HIP_MEMORY_SCOPE_AGENT);
        int it = 0;  // xg[t+1] ready? (workers run far ahead; usually instant)
        while (__hip_atomic_load(done + ((size_t)(t + 1) << 5),
                                 __ATOMIC_RELAXED, __HIP_MEMORY_SCOPE_AGENT) < 32u) {
          __builtin_amdgcn_s_sleep(1);
          if (++it > (1 << 24)) break;
        }
      }
      __syncthreads();  // gate the prefetch on readiness
      {
        const unsigned short* q = xp + (size_t)(t + 1) * GG * BB;
        nxi = q[0];
        nxf = q[(size_t)HH * BB];
        nxc = q[(size_t)2 * HH * BB];
        nxo = q[(size_t)3 * HH * BB];
      }
      if (tid < 64) {
        int it = 0;
        for (;;) {
          unsigned v = __hip_atomic_load(flags + (tid << 5), __ATOMIC_RELAXED, __HIP_MEMORY_SCOPE_AGENT);
          if (v >= (unsigned)(t + 2)) break;
          __builtin_amdgcn_s_sleep(1);
          if (++it > (1 << 24)) break;
        }
        __builtin_amdgcn_fence(__ATOMIC_ACQUIRE, "agent");
      }
      asm volatile("" ::: "memory");
      __syncthreads();
    }
    xi = nxi; xf = nxf; xc = nxc; xo = nxo;
  }
}

// ---------- out[m][n] = dot(hs[m][:], fc_W[n][:]) + fc_b[n] ----------
__global__ __launch_bounds__(256) void k_fc(const unsigned short* __restrict__ hs,
                                            const unsigned short* __restrict__ fw,
                                            const float* __restrict__ fb,
                                            float* __restrict__ out) {
  int mb = blockIdx.x * 64, nb = blockIdx.y * 64;
  int wave = threadIdx.x >> 6, lane = threadIdx.x & 63;
  int lr = lane & 15, ko = lane >> 4;
  int rowA = mb + wave * 16 + lr;
  f32x4 acc[4] = {{0, 0, 0, 0}, {0, 0, 0, 0}, {0, 0, 0, 0}, {0, 0, 0, 0}};
#pragma unroll 8
  for (int ks = 0; ks < 32; ++ks) {
    int k = ks * 32 + ko * 8;
    short8 a = *(const short8*)(hs + (size_t)rowA * HH + k);
#pragma unroll
    for (int nt = 0; nt < 4; ++nt) {
      short8 bb = *(const short8*)(fw + (size_t)(nb + nt * 16 + lr) * HH + k);
      acc[nt] = __builtin_amdgcn_mfma_f32_16x16x32_bf16(a, bb, acc[nt], 0, 0, 0);
    }
  }
  int rD = mb + wave * 16 + ko * 4;
#pragma unroll
  for (int nt = 0; nt < 4; ++nt) {
    int col = nb + nt * 16 + lr;
    float bias = fb[col];
#pragma unroll
    for (int q = 0; q < 4; ++q)
      out[(size_t)(rD + q) * OO + col] = acc[nt][q] + bias;
  }
}

extern "C" void kernel_launch(void* const* d_in, const int* in_sizes, int n_in,
                              void* d_out, int out_size, void* d_ws, size_t ws_size,
                              hipStream_t stream) {
  (void)in_sizes; (void)n_in; (void)out_size; (void)ws_size;
  const float* x   = (const float*)d_in[0];
  const float* h0  = (const float*)d_in[1];
  const float* c0  = (const float*)d_in[2];
  const float* wih = (const float*)d_in[3];
  const float* whh = (const float*)d_in[4];
  const float* bih = (const float*)d_in[5];
  const float* bhh = (const float*)d_in[6];
  const float* fcw = (const float*)d_in[7];
  const float* fcb = (const float*)d_in[8];
  float* out = (float*)d_out;

  // workspace carve (~181 MB)
  char* w = (char*)d_ws;
  unsigned short* xg   = (unsigned short*)w; w += (size_t)TT * GG * BB * 2;  // 128 MiB
  unsigned short* hsb  = (unsigned short*)w; w += (size_t)BB * TT * HH * 2;  //  32 MiB
  unsigned short* xb   = (unsigned short*)w; w += (size_t)BB * TT * II * 2;  //  16 MiB
  unsigned short* wbb  = (unsigned short*)w; w += (size_t)GG * II * 2;       //   4 MiB
  unsigned short* fwb  = (unsigned short*)w; w += (size_t)OO * HH * 2;       // 512 KiB
  unsigned short* hbuf = (unsigned short*)w; w += (size_t)2 * BB * HH * 2;   // 128 KiB
  unsigned* flags      = (unsigned*)w;       w += 64 * 128;                  // 8 KiB (padded)
  unsigned* done       = (unsigned*)w;       w += 512 * 128;                 // 64 KiB (padded)

  hipMemsetAsync(flags, 0, 64 * 128 + 512 * 128, stream);
  k_convert<<<(BB * TT * II / 8) / 256, 256, 0, stream>>>(x, xb, BB * TT * II / 8);
  k_convert<<<(GG * II / 8) / 256, 256, 0, stream>>>(wih, wbb, GG * II / 8);
  k_convert<<<(OO * HH / 8) / 256, 256, 0, stream>>>(fcw, fwb, OO * HH / 8);
  k_main<<<NSCAN + NWORK, 512, 0, stream>>>(whh, xb, wbb, bih, bhh, xg, h0, c0,
                                            hbuf, hsb,
                                            out + (size_t)BB * TT * OO, flags, done);
  k_fc<<<dim3(BB * TT / 64, OO / 64), 256, 0, stream>>>(hsb, fwb, fcb, out);
}